// Round 4
// baseline (564.435 us; speedup 1.0000x reference)
//
#include <hip/hip_runtime.h>
#include <hip/hip_bf16.h>

typedef __attribute__((ext_vector_type(8))) short bf16x8;
typedef __attribute__((ext_vector_type(4))) short bf16x4;
typedef __attribute__((ext_vector_type(4))) float f32x4;

#define MFMA32(a,b,c) __builtin_amdgcn_mfma_f32_16x16x32_bf16(a,b,c,0,0,0)

#if __has_builtin(__builtin_amdgcn_mfma_f32_16x16x16bf16_1k)
#define MFMA16(a,b,c) __builtin_amdgcn_mfma_f32_16x16x16bf16_1k(a,b,c,0,0,0)
#else
static __device__ __forceinline__ f32x4 mfma16_asm(bf16x4 a, bf16x4 b, f32x4 c){
  asm volatile("v_mfma_f32_16x16x16_bf16 %0, %1, %2, %0" : "+v"(c) : "v"(a), "v"(b));
  return c;
}
#define MFMA16(a,b,c) mfma16_asm(a,b,c)
#endif

#define NEGV -65504.0f

__device__ __forceinline__ unsigned short f2bf(float f){
  union { float f; unsigned u; } x; x.f = f;
  unsigned r = x.u + 0x7fffu + ((x.u >> 16) & 1u);
  return (unsigned short)(r >> 16);
}

__device__ __forceinline__ unsigned cvtpk(float a, float b){
  unsigned r;
  asm volatile("v_cvt_pk_bf16_f32 %0, %1, %2" : "=v"(r) : "v"(a), "v"(b));
  return r;   // a -> low 16, b -> high 16 (T12 recipe)
}

// ---------------- fused fp32 -> bf16 convert for x, W_qkv, W_proj ----------------
// outputs are contiguous in ws: [xb | wqb | wpb]
__global__ void cvt_all(const float* __restrict__ x, const float* __restrict__ wq,
                        const float* __restrict__ wp, unsigned short* __restrict__ out){
  int i = blockIdx.x * 256 + threadIdx.x;        // 0 .. 2162687 float4 groups
  const float* src; int j;
  if (i < 1572864)      { src = x;  j = i; }
  else if (i < 2015232) { src = wq; j = i - 1572864; }
  else                  { src = wp; j = i - 2015232; }
  float4 f = ((const float4*)src)[j];
  ushort4 u;
  u.x = f2bf(f.x); u.y = f2bf(f.y); u.z = f2bf(f.z); u.w = f2bf(f.w);
  ((ushort4*)out)[i] = u;
}

// ---------------- QKV GEMM: X[8192,768] @ W[2304,768]^T + b ----------------
// scatter into q (scaled by 0.125), k, v as [B*H=96, N=1024, D=64] bf16
__global__ __launch_bounds__(256) void gemm_qkv(
    const unsigned short* __restrict__ X,
    const unsigned short* __restrict__ W,
    const float* __restrict__ bias,
    unsigned short* __restrict__ Qd,
    unsigned short* __restrict__ Kd,
    unsigned short* __restrict__ Vd)
{
  const int K = 768;
  int bid = blockIdx.x;
  int bm = bid & 63;
  int bn = bid >> 6;
  int wave = threadIdx.x >> 6;
  int lane = threadIdx.x & 63;
  int lo = lane & 15, g = lane >> 4;
  int row0 = bm * 128 + (wave >> 1) * 64;
  int col0 = bn * 128 + (wave & 1) * 64;

  f32x4 acc[4][4] = {};
  for (int k0 = 0; k0 < K; k0 += 32) {
    bf16x8 a[4], b[4];
    int ko = k0 + g * 8;
#pragma unroll
    for (int i = 0; i < 4; ++i)
      a[i] = *(const bf16x8*)(X + (size_t)(row0 + i*16 + lo) * K + ko);
#pragma unroll
    for (int i = 0; i < 4; ++i)
      b[i] = *(const bf16x8*)(W + (size_t)(col0 + i*16 + lo) * K + ko);
#pragma unroll
    for (int mi = 0; mi < 4; ++mi)
#pragma unroll
      for (int ni = 0; ni < 4; ++ni)
        acc[mi][ni] = MFMA32(a[mi], b[ni], acc[mi][ni]);
  }
#pragma unroll
  for (int ni = 0; ni < 4; ++ni) {
    int col = col0 + ni*16 + lo;
    float bc = bias[col];
    int which = col / 768;
    int rem = col - which * 768;
    int h = rem >> 6, d = rem & 63;
    unsigned short* dst = (which == 0) ? Qd : (which == 1) ? Kd : Vd;
    float scale = (which == 0) ? 0.125f : 1.0f;
#pragma unroll
    for (int mi = 0; mi < 4; ++mi) {
#pragma unroll
      for (int r = 0; r < 4; ++r) {
        int row = row0 + mi*16 + g*4 + r;
        int bb = row >> 10, n = row & 1023;
        dst[(((size_t)bb*12 + h)*1024 + n)*64 + d] = f2bf((acc[mi][ni][r] + bc) * scale);
      }
    }
  }
}

// ---------------- V transpose: [96][1024][64] -> [96][64][1024] ----------------
__global__ __launch_bounds__(256) void vtrans(const unsigned short* __restrict__ V,
                                              unsigned short* __restrict__ Vt){
  __shared__ unsigned short t[64][72];   // 72 pad: 16B-aligned rows, conflict-diffused
  int bh = blockIdx.y;
  int n0 = blockIdx.x * 64;
  int tid = threadIdx.x;
  int nl = tid >> 2;
  int dq = (tid & 3) * 16;
  const unsigned short* src = V + ((size_t)bh*1024 + n0 + nl)*64 + dq;
  bf16x8 a0 = *(const bf16x8*)(src);
  bf16x8 a1 = *(const bf16x8*)(src + 8);
  *(bf16x8*)&t[nl][dq]     = a0;
  *(bf16x8*)&t[nl][dq + 8] = a1;
  __syncthreads();
  int d  = tid >> 2;
  int nq = (tid & 3) * 16;
  union { unsigned short s[16]; bf16x8 v[2]; } pk;
#pragma unroll
  for (int j = 0; j < 16; ++j) pk.s[j] = t[nq + j][d];
  unsigned short* dst = Vt + ((size_t)bh*64 + d)*1024 + n0 + nq;
  *(bf16x8*)(dst)     = pk.v[0];
  *(bf16x8*)(dst + 8) = pk.v[1];
}

// ---------------- fused attention core (kv-tile = 32, K-prefetch, Vt loads) ----
// grid (16 qblocks, 96 y); y = h*8 + b (h-major for bias L2/L3 reuse)
__global__ __launch_bounds__(256, 4) void attn_kernel(
    const unsigned short* __restrict__ Qd,
    const unsigned short* __restrict__ Kd,
    const unsigned short* __restrict__ Vt,   // [96][64][1024]
    const float* __restrict__ bias,          // [12,1024,1024] fp32
    const int* __restrict__ mask,            // [8,1024,1024] int32 (bool)
    float* __restrict__ out1,                // [96,1024,1024] fp32
    unsigned short* __restrict__ ctx)        // [8192,768] bf16
{
  const int N = 1024, D = 64;
  int y = blockIdx.y;
  int h = y >> 3, b = y & 7;
  int bh = b * 12 + h;
  int wave = threadIdx.x >> 6, lane = threadIdx.x & 63;
  int lo = lane & 15, g = lane >> 4;
  int qrow = blockIdx.x * 64 + wave * 16 + lo;

  const size_t qoff = ((size_t)bh * N + qrow) * D;
  bf16x8 qf0 = *(const bf16x8*)(Qd + qoff + g*8);        // B-frag: col=q, k=d
  bf16x8 qf1 = *(const bf16x8*)(Qd + qoff + 32 + g*8);

  const float* bias_row = bias + ((size_t)h * N + qrow) * N;
  const int* mask_row   = mask + ((size_t)b * N + qrow) * N;
  float* out_row        = out1 + ((size_t)bh * N + qrow) * N;
  const unsigned short* pK = Kd + (size_t)bh * N * D + (size_t)lo * D + g * 8;
  const unsigned short* pV = Vt + (size_t)bh * D * N + g * 4;

  float m_run = -INFINITY, l_run = 0.0f;
  f32x4 o[4] = {};   // O^T: lane holds q=lo, d = c*16 + g*4 + reg

  // preload K tile 0 (two 16-row subtiles x two 32-d halves)
  bf16x8 kc00 = *(const bf16x8*)(pK);
  bf16x8 kc01 = *(const bf16x8*)(pK + 32);
  bf16x8 kc10 = *(const bf16x8*)(pK + 16*D);
  bf16x8 kc11 = *(const bf16x8*)(pK + 16*D + 32);

  for (int it = 0; it < 32; ++it) {
    int kv = it * 32;
    // --- prefetch next K tile (head of next iteration's chain) ---
    bf16x8 kn00, kn01, kn10, kn11;
    if (it < 31) {
      const unsigned short* pKn = pK + (size_t)(kv + 32) * D;
      kn00 = *(const bf16x8*)(pKn);
      kn01 = *(const bf16x8*)(pKn + 32);
      kn10 = *(const bf16x8*)(pKn + 16*D);
      kn11 = *(const bf16x8*)(pKn + 16*D + 32);
    }
    // --- mask / bias / V loads for this tile (independent of MFMA) ---
    int mc0 = kv + g*4, mc1 = kv + 16 + g*4;
    int4  mv0 = *(const int4*)(mask_row + mc0);
    int4  mv1 = *(const int4*)(mask_row + mc1);
    float4 bi0 = *(const float4*)(bias_row + mc0);
    float4 bi1 = *(const float4*)(bias_row + mc1);
    bf16x4 vf0[4], vf1[4];
#pragma unroll
    for (int c = 0; c < 4; ++c) {
      const unsigned short* vrow = pV + (size_t)(c*16 + lo) * N + kv;
      vf0[c] = *(const bf16x4*)(vrow);
      vf1[c] = *(const bf16x4*)(vrow + 16);
    }

    // --- QK^T (swapped): s[r] = S[q=lo][kpos = kv(+16) + g*4 + r] ---
    f32x4 s0 = {}, s1 = {};
    s0 = MFMA32(kc00, qf0, s0);
    s0 = MFMA32(kc01, qf1, s0);
    s1 = MFMA32(kc10, qf0, s1);
    s1 = MFMA32(kc11, qf1, s1);

    float sp0 = (mv0.x ? NEGV : s0[0]) + bi0.x;
    float sp1 = (mv0.y ? NEGV : s0[1]) + bi0.y;
    float sp2 = (mv0.z ? NEGV : s0[2]) + bi0.z;
    float sp3 = (mv0.w ? NEGV : s0[3]) + bi0.w;
    float sp4 = (mv1.x ? NEGV : s1[0]) + bi1.x;
    float sp5 = (mv1.y ? NEGV : s1[1]) + bi1.y;
    float sp6 = (mv1.z ? NEGV : s1[2]) + bi1.z;
    float sp7 = (mv1.w ? NEGV : s1[3]) + bi1.w;
    f32x4 ov0; ov0[0] = sp0; ov0[1] = sp1; ov0[2] = sp2; ov0[3] = sp3;
    f32x4 ov1; ov1[0] = sp4; ov1[1] = sp5; ov1[2] = sp6; ov1[3] = sp7;
    __builtin_nontemporal_store(ov0, (f32x4*)(out_row + mc0));  // write-once dump
    __builtin_nontemporal_store(ov1, (f32x4*)(out_row + mc1));

    // --- online softmax over 32 cols (row in lanes {lo, lo+16, lo+32, lo+48}) ---
    float tmax = fmaxf(fmaxf(fmaxf(sp0, sp1), fmaxf(sp2, sp3)),
                       fmaxf(fmaxf(sp4, sp5), fmaxf(sp6, sp7)));
    tmax = fmaxf(tmax, __shfl_xor(tmax, 16));
    tmax = fmaxf(tmax, __shfl_xor(tmax, 32));
    float mnew = fmaxf(m_run, tmax);
    float alpha = __expf(m_run - mnew);
    float p0 = __expf(sp0 - mnew), p1 = __expf(sp1 - mnew);
    float p2 = __expf(sp2 - mnew), p3 = __expf(sp3 - mnew);
    float p4 = __expf(sp4 - mnew), p5 = __expf(sp5 - mnew);
    float p6 = __expf(sp6 - mnew), p7 = __expf(sp7 - mnew);
    float ts = ((p0 + p1) + (p2 + p3)) + ((p4 + p5) + (p6 + p7));
    ts += __shfl_xor(ts, 16);
    ts += __shfl_xor(ts, 32);
    l_run = l_run * alpha + ts;
    m_run = mnew;

    // --- pack P to bf16 (hardware cvt_pk; a->low, b->high) ---
    union { unsigned u[2]; bf16x4 h; } q0, q1;
    q0.u[0] = cvtpk(p0, p1); q0.u[1] = cvtpk(p2, p3);
    q1.u[0] = cvtpk(p4, p5); q1.u[1] = cvtpk(p6, p7);

    // --- PV: o[c] += Vt-frag x P-frag (16x16x16) ---
#pragma unroll
    for (int c = 0; c < 4; ++c) {
      o[c][0] *= alpha; o[c][1] *= alpha; o[c][2] *= alpha; o[c][3] *= alpha;
      o[c] = MFMA16(vf0[c], q0.h, o[c]);
      o[c] = MFMA16(vf1[c], q1.h, o[c]);
    }

    if (it < 31) { kc00 = kn00; kc01 = kn01; kc10 = kn10; kc11 = kn11; }
  }

  float inv = 1.0f / l_run;
  size_t crow = ((size_t)b * N + qrow) * 768 + h * 64;
#pragma unroll
  for (int c = 0; c < 4; ++c) {
    ushort4 u;
    u.x = f2bf(o[c][0] * inv);
    u.y = f2bf(o[c][1] * inv);
    u.z = f2bf(o[c][2] * inv);
    u.w = f2bf(o[c][3] * inv);
    *(ushort4*)(ctx + crow + c*16 + g*4) = u;
  }
}

// ---------------- proj GEMM: ctx[8192,768] @ Wp[768,768]^T + b -> fp32 ----------------
__global__ __launch_bounds__(256) void gemm_proj(
    const unsigned short* __restrict__ X,
    const unsigned short* __restrict__ W,
    const float* __restrict__ bias,
    float* __restrict__ out)
{
  const int K = 768;
  int bid = blockIdx.x;
  int bm = bid & 63;
  int bn = bid >> 6;
  int wave = threadIdx.x >> 6;
  int lane = threadIdx.x & 63;
  int lo = lane & 15, g = lane >> 4;
  int row0 = bm * 128 + (wave >> 1) * 64;
  int col0 = bn * 128 + (wave & 1) * 64;

  f32x4 acc[4][4] = {};
  for (int k0 = 0; k0 < K; k0 += 32) {
    bf16x8 a[4], b[4];
    int ko = k0 + g * 8;
#pragma unroll
    for (int i = 0; i < 4; ++i)
      a[i] = *(const bf16x8*)(X + (size_t)(row0 + i*16 + lo) * K + ko);
#pragma unroll
    for (int i = 0; i < 4; ++i)
      b[i] = *(const bf16x8*)(W + (size_t)(col0 + i*16 + lo) * K + ko);
#pragma unroll
    for (int mi = 0; mi < 4; ++mi)
#pragma unroll
      for (int ni = 0; ni < 4; ++ni)
        acc[mi][ni] = MFMA32(a[mi], b[ni], acc[mi][ni]);
  }
#pragma unroll
  for (int ni = 0; ni < 4; ++ni) {
    int col = col0 + ni*16 + lo;
    float bc = bias[col];
#pragma unroll
    for (int mi = 0; mi < 4; ++mi) {
#pragma unroll
      for (int r = 0; r < 4; ++r) {
        int row = row0 + mi*16 + g*4 + r;
        out[(size_t)row * 768 + col] = acc[mi][ni][r] + bc;
      }
    }
  }
}

extern "C" void kernel_launch(void* const* d_in, const int* in_sizes, int n_in,
                              void* d_out, int out_size, void* d_ws, size_t ws_size,
                              hipStream_t stream) {
  const float* x            = (const float*)d_in[0];
  const float* rel_pos_bias = (const float*)d_in[1];
  const int* mask           = (const int*)d_in[2];
  const float* Wqkv         = (const float*)d_in[3];
  const float* bqkv         = (const float*)d_in[4];
  const float* Wproj        = (const float*)d_in[5];
  const float* bproj        = (const float*)d_in[6];

  float* out0 = (float*)d_out;                         // [8,1024,768]
  float* out1 = out0 + (size_t)8 * 1024 * 768;         // [8,12,1024,1024]

  // workspace layout (bytes), total ~67.6 MB
  char* ws = (char*)d_ws;
  unsigned short* xb  = (unsigned short*)(ws);                 // 12,582,912 (dead after gemm_qkv)
  unsigned short* wqb = (unsigned short*)(ws + 12582912);      //  3,538,944
  unsigned short* wpb = (unsigned short*)(ws + 16121856);      //  1,179,648
  unsigned short* Qb  = (unsigned short*)(ws + 17301504);      // 12,582,912
  unsigned short* Kb  = (unsigned short*)(ws + 29884416);      // 12,582,912
  unsigned short* Vb  = (unsigned short*)(ws + 42467328);      // 12,582,912
  unsigned short* ctx = (unsigned short*)(ws + 55050240);      // 12,582,912
  unsigned short* Vtb = xb;                                    // reuse xb region for V^T

  cvt_all<<<8448, 256, 0, stream>>>(x, Wqkv, Wproj, xb);

  gemm_qkv<<<1152, 256, 0, stream>>>(xb, wqb, bqkv, Qb, Kb, Vb);

  vtrans<<<dim3(16, 96), 256, 0, stream>>>(Vb, Vtb);

  attn_kernel<<<dim3(16, 96), 256, 0, stream>>>(Qb, Kb, Vtb, rel_pos_bias, mask,
                                                out1, ctx);

  gemm_proj<<<384, 256, 0, stream>>>(ctx, wpb, bproj, out0);
}

// Round 5
// 456.559 us; speedup vs baseline: 1.2363x; 1.2363x over previous
//
#include <hip/hip_runtime.h>
#include <hip/hip_bf16.h>

typedef __attribute__((ext_vector_type(8))) short bf16x8;
typedef __attribute__((ext_vector_type(4))) short bf16x4;
typedef __attribute__((ext_vector_type(4))) float f32x4;

#define MFMA32(a,b,c) __builtin_amdgcn_mfma_f32_16x16x32_bf16(a,b,c,0,0,0)

#if __has_builtin(__builtin_amdgcn_mfma_f32_16x16x16bf16_1k)
#define MFMA16(a,b,c) __builtin_amdgcn_mfma_f32_16x16x16bf16_1k(a,b,c,0,0,0)
#else
static __device__ __forceinline__ f32x4 mfma16_asm(bf16x4 a, bf16x4 b, f32x4 c){
  asm volatile("v_mfma_f32_16x16x16_bf16 %0, %1, %2, %0" : "+v"(c) : "v"(a), "v"(b));
  return c;
}
#define MFMA16(a,b,c) mfma16_asm(a,b,c)
#endif

#define NEGV -65504.0f

__device__ __forceinline__ unsigned short f2bf(float f){
  union { float f; unsigned u; } x; x.f = f;
  unsigned r = x.u + 0x7fffu + ((x.u >> 16) & 1u);
  return (unsigned short)(r >> 16);
}

__device__ __forceinline__ unsigned cvtpk(float a, float b){
  unsigned r;
  asm volatile("v_cvt_pk_bf16_f32 %0, %1, %2" : "=v"(r) : "v"(a), "v"(b));
  return r;   // a -> low 16, b -> high 16
}

// ---------------- fused fp32 -> bf16 convert for x, W_qkv, W_proj ----------------
__global__ void cvt_all(const float* __restrict__ x, const float* __restrict__ wq,
                        const float* __restrict__ wp, unsigned short* __restrict__ out){
  int i = blockIdx.x * 256 + threadIdx.x;
  const float* src; int j;
  if (i < 1572864)      { src = x;  j = i; }
  else if (i < 2015232) { src = wq; j = i - 1572864; }
  else                  { src = wp; j = i - 2015232; }
  float4 f = ((const float4*)src)[j];
  ushort4 u;
  u.x = f2bf(f.x); u.y = f2bf(f.y); u.z = f2bf(f.z); u.w = f2bf(f.w);
  ((ushort4*)out)[i] = u;
}

// ---------------- LDS-staged QKV GEMM: X[8192,768] @ W[2304,768]^T + b ----------
// 128x128 tile, BK=32, 4 waves (2x2 of 64x64), padded-40 LDS rows (<=2-way conflicts)
__global__ __launch_bounds__(256) void gemm_qkv(
    const unsigned short* __restrict__ X,
    const unsigned short* __restrict__ W,
    const float* __restrict__ bias,
    unsigned short* __restrict__ Qd,
    unsigned short* __restrict__ Kd,
    unsigned short* __restrict__ Vd)
{
  __shared__ unsigned short As[128*40];
  __shared__ unsigned short Bs[128*40];
  const int K = 768;
  int tid = threadIdx.x;
  int bm = blockIdx.x & 63;
  int bn = blockIdx.x >> 6;
  int wave = tid >> 6, lane = tid & 63;
  int lo = lane & 15, g = lane >> 4;
  int wr = (wave >> 1) * 64, wc = (wave & 1) * 64;
  int row0 = bm * 128, col0 = bn * 128;

  int sr = tid >> 1;                  // staging row 0..127
  int sc = (tid & 1) * 16;            // staging col half
  const unsigned short* gA = X + (size_t)(row0 + sr) * K + sc;
  const unsigned short* gB = W + (size_t)(col0 + sr) * K + sc;
  unsigned short* sA = &As[sr * 40 + sc];
  unsigned short* sB = &Bs[sr * 40 + sc];

  f32x4 acc[4][4] = {};
  for (int k0 = 0; k0 < K; k0 += 32) {
    bf16x8 a0 = *(const bf16x8*)(gA + k0);
    bf16x8 a1 = *(const bf16x8*)(gA + k0 + 8);
    bf16x8 b0 = *(const bf16x8*)(gB + k0);
    bf16x8 b1 = *(const bf16x8*)(gB + k0 + 8);
    __syncthreads();
    *(bf16x8*)(sA)     = a0;
    *(bf16x8*)(sA + 8) = a1;
    *(bf16x8*)(sB)     = b0;
    *(bf16x8*)(sB + 8) = b1;
    __syncthreads();
    bf16x8 af[4], bf[4];
#pragma unroll
    for (int i = 0; i < 4; ++i) af[i] = *(const bf16x8*)&As[(wr + i*16 + lo)*40 + g*8];
#pragma unroll
    for (int i = 0; i < 4; ++i) bf[i] = *(const bf16x8*)&Bs[(wc + i*16 + lo)*40 + g*8];
#pragma unroll
    for (int mi = 0; mi < 4; ++mi)
#pragma unroll
      for (int ni = 0; ni < 4; ++ni)
        acc[mi][ni] = MFMA32(af[mi], bf[ni], acc[mi][ni]);
  }
  int orow0 = row0 + wr, ocol0 = col0 + wc;
#pragma unroll
  for (int ni = 0; ni < 4; ++ni) {
    int col = ocol0 + ni*16 + lo;
    float bc = bias[col];
    int which = col / 768;
    int rem = col - which * 768;
    int h = rem >> 6, d = rem & 63;
    unsigned short* dst = (which == 0) ? Qd : (which == 1) ? Kd : Vd;
    float scale = (which == 0) ? 0.125f : 1.0f;
#pragma unroll
    for (int mi = 0; mi < 4; ++mi) {
#pragma unroll
      for (int r = 0; r < 4; ++r) {
        int row = orow0 + mi*16 + g*4 + r;
        int bb = row >> 10, n = row & 1023;
        dst[(((size_t)bb*12 + h)*1024 + n)*64 + d] = f2bf((acc[mi][ni][r] + bc) * scale);
      }
    }
  }
}

// ---------------- V transpose: [96][1024][64] -> [96][64][1024] ----------------
__global__ __launch_bounds__(256) void vtrans(const unsigned short* __restrict__ V,
                                              unsigned short* __restrict__ Vt){
  __shared__ unsigned short t[64][72];
  int bh = blockIdx.y;
  int n0 = blockIdx.x * 64;
  int tid = threadIdx.x;
  int nl = tid >> 2;
  int dq = (tid & 3) * 16;
  const unsigned short* src = V + ((size_t)bh*1024 + n0 + nl)*64 + dq;
  bf16x8 a0 = *(const bf16x8*)(src);
  bf16x8 a1 = *(const bf16x8*)(src + 8);
  *(bf16x8*)&t[nl][dq]     = a0;
  *(bf16x8*)&t[nl][dq + 8] = a1;
  __syncthreads();
  int d  = tid >> 2;
  int nq = (tid & 3) * 16;
  union { unsigned short s[16]; bf16x8 v[2]; } pk;
#pragma unroll
  for (int j = 0; j < 16; ++j) pk.s[j] = t[nq + j][d];
  unsigned short* dst = Vt + ((size_t)bh*64 + d)*1024 + n0 + nq;
  *(bf16x8*)(dst)     = pk.v[0];
  *(bf16x8*)(dst + 8) = pk.v[1];
}

// ---------------- fused attention core ----------------
// kv-tile=32; K/mask/bias double-buffered in regs; V issued early; sched_barrier
// pins prefetch; deferred cross-lane max (THR=8) + deferred l-reduction.
__global__ __launch_bounds__(256, 4) void attn_kernel(
    const unsigned short* __restrict__ Qd,
    const unsigned short* __restrict__ Kd,
    const unsigned short* __restrict__ Vt,   // [96][64][1024]
    const float* __restrict__ bias,          // [12,1024,1024] fp32
    const int* __restrict__ mask,            // [8,1024,1024] int32 (bool)
    float* __restrict__ out1,                // [96,1024,1024] fp32
    unsigned short* __restrict__ ctx)        // [8192,768] bf16
{
  const int N = 1024, D = 64;
  int y = blockIdx.y;
  int h = y >> 3, b = y & 7;
  int bh = b * 12 + h;
  int wave = threadIdx.x >> 6, lane = threadIdx.x & 63;
  int lo = lane & 15, g = lane >> 4;
  int qrow = blockIdx.x * 64 + wave * 16 + lo;

  const size_t qoff = ((size_t)bh * N + qrow) * D;
  bf16x8 qf0 = *(const bf16x8*)(Qd + qoff + g*8);
  bf16x8 qf1 = *(const bf16x8*)(Qd + qoff + 32 + g*8);

  const float* bias_row = bias + ((size_t)h * N + qrow) * N;
  const int* mask_row   = mask + ((size_t)b * N + qrow) * N;
  float* out_row        = out1 + ((size_t)bh * N + qrow) * N;
  const unsigned short* pK = Kd + (size_t)bh * N * D + (size_t)lo * D + g * 8;
  const unsigned short* pV = Vt + (size_t)bh * D * N + g * 4;

  float m_run = -INFINITY, l_part = 0.0f;
  f32x4 o[4] = {};   // O^T: lane holds q=lo, d = c*16 + g*4 + reg

  // tile-0 current-buffer loads
  bf16x8 kc0 = *(const bf16x8*)(pK);
  bf16x8 kc1 = *(const bf16x8*)(pK + 32);
  bf16x8 kc2 = *(const bf16x8*)(pK + 16*D);
  bf16x8 kc3 = *(const bf16x8*)(pK + 16*D + 32);
  int4   mvc0 = *(const int4*)(mask_row + g*4);
  int4   mvc1 = *(const int4*)(mask_row + 16 + g*4);
  float4 bic0 = *(const float4*)(bias_row + g*4);
  float4 bic1 = *(const float4*)(bias_row + 16 + g*4);

  for (int it = 0; it < 32; ++it) {
    int kv  = it * 32;
    int kvn = (it == 31) ? 0 : kv + 32;     // clamp: last prefetch discarded

    // ---- prefetch next K / mask / bias (one full tile ahead) ----
    const unsigned short* pKn = pK + (size_t)kvn * D;
    bf16x8 kn0 = *(const bf16x8*)(pKn);
    bf16x8 kn1 = *(const bf16x8*)(pKn + 32);
    bf16x8 kn2 = *(const bf16x8*)(pKn + 16*D);
    bf16x8 kn3 = *(const bf16x8*)(pKn + 16*D + 32);
    int4   mvn0 = *(const int4*)(mask_row + kvn + g*4);
    int4   mvn1 = *(const int4*)(mask_row + kvn + 16 + g*4);
    float4 bin0 = *(const float4*)(bias_row + kvn + g*4);
    float4 bin1 = *(const float4*)(bias_row + kvn + 16 + g*4);
    // ---- current V (used late in iter -> latency covered by softmax) ----
    bf16x4 vf0[4], vf1[4];
#pragma unroll
    for (int c = 0; c < 4; ++c) {
      const unsigned short* vrow = pV + (size_t)(c*16 + lo) * N + kv;
      vf0[c] = *(const bf16x4*)(vrow);
      vf1[c] = *(const bf16x4*)(vrow + 16);
    }
    __builtin_amdgcn_sched_barrier(0);   // pin loads above the compute

    // ---- QK^T (swapped): s[r] = S[q=lo][kpos = kv(+16) + g*4 + r] ----
    f32x4 s0 = {}, s1 = {};
    s0 = MFMA32(kc0, qf0, s0);
    s0 = MFMA32(kc1, qf1, s0);
    s1 = MFMA32(kc2, qf0, s1);
    s1 = MFMA32(kc3, qf1, s1);

    int mc0 = kv + g*4, mc1 = kv + 16 + g*4;
    float sp0 = (mvc0.x ? NEGV : s0[0]) + bic0.x;
    float sp1 = (mvc0.y ? NEGV : s0[1]) + bic0.y;
    float sp2 = (mvc0.z ? NEGV : s0[2]) + bic0.z;
    float sp3 = (mvc0.w ? NEGV : s0[3]) + bic0.w;
    float sp4 = (mvc1.x ? NEGV : s1[0]) + bic1.x;
    float sp5 = (mvc1.y ? NEGV : s1[1]) + bic1.y;
    float sp6 = (mvc1.z ? NEGV : s1[2]) + bic1.z;
    float sp7 = (mvc1.w ? NEGV : s1[3]) + bic1.w;
    f32x4 ov0; ov0[0] = sp0; ov0[1] = sp1; ov0[2] = sp2; ov0[3] = sp3;
    f32x4 ov1; ov1[0] = sp4; ov1[1] = sp5; ov1[2] = sp6; ov1[3] = sp7;
    __builtin_nontemporal_store(ov0, (f32x4*)(out_row + mc0));
    __builtin_nontemporal_store(ov1, (f32x4*)(out_row + mc1));

    // ---- deferred-max online softmax: no cross-lane ops on the common path ----
    float lmax = fmaxf(fmaxf(fmaxf(sp0, sp1), fmaxf(sp2, sp3)),
                       fmaxf(fmaxf(sp4, sp5), fmaxf(sp6, sp7)));
    if (!__all(lmax <= m_run + 8.0f)) {          // rare: max grew
      float tmax = fmaxf(lmax, __shfl_xor(lmax, 16));
      tmax = fmaxf(tmax, __shfl_xor(tmax, 32));
      float mnew = fmaxf(m_run, tmax);
      float alpha = __expf(m_run - mnew);
      l_part *= alpha;
#pragma unroll
      for (int c = 0; c < 4; ++c) {
        o[c][0] *= alpha; o[c][1] *= alpha; o[c][2] *= alpha; o[c][3] *= alpha;
      }
      m_run = mnew;
    }
    float p0 = __expf(sp0 - m_run), p1 = __expf(sp1 - m_run);
    float p2 = __expf(sp2 - m_run), p3 = __expf(sp3 - m_run);
    float p4 = __expf(sp4 - m_run), p5 = __expf(sp5 - m_run);
    float p6 = __expf(sp6 - m_run), p7 = __expf(sp7 - m_run);
    l_part += ((p0 + p1) + (p2 + p3)) + ((p4 + p5) + (p6 + p7));

    union { unsigned u[2]; bf16x4 h; } q0, q1;
    q0.u[0] = cvtpk(p0, p1); q0.u[1] = cvtpk(p2, p3);
    q1.u[0] = cvtpk(p4, p5); q1.u[1] = cvtpk(p6, p7);

#pragma unroll
    for (int c = 0; c < 4; ++c) {
      o[c] = MFMA16(vf0[c], q0.h, o[c]);
      o[c] = MFMA16(vf1[c], q1.h, o[c]);
    }

    kc0 = kn0; kc1 = kn1; kc2 = kn2; kc3 = kn3;
    mvc0 = mvn0; mvc1 = mvn1; bic0 = bin0; bic1 = bin1;
  }

  // deferred l reduction (row = lanes {lo, lo+16, lo+32, lo+48})
  l_part += __shfl_xor(l_part, 16);
  l_part += __shfl_xor(l_part, 32);
  float inv = 1.0f / l_part;

  size_t crow = ((size_t)b * N + qrow) * 768 + h * 64;
#pragma unroll
  for (int c = 0; c < 4; ++c) {
    ushort4 u;
    u.x = f2bf(o[c][0] * inv);
    u.y = f2bf(o[c][1] * inv);
    u.z = f2bf(o[c][2] * inv);
    u.w = f2bf(o[c][3] * inv);
    *(ushort4*)(ctx + crow + c*16 + g*4) = u;
  }
}

// ---------------- LDS-staged proj GEMM: ctx[8192,768] @ Wp[768,768]^T + b ------
__global__ __launch_bounds__(256) void gemm_proj(
    const unsigned short* __restrict__ X,
    const unsigned short* __restrict__ W,
    const float* __restrict__ bias,
    float* __restrict__ out)
{
  __shared__ unsigned short As[128*40];
  __shared__ unsigned short Bs[128*40];
  const int K = 768;
  int tid = threadIdx.x;
  int bm = blockIdx.x & 63;
  int bn = blockIdx.x >> 6;
  int wave = tid >> 6, lane = tid & 63;
  int lo = lane & 15, g = lane >> 4;
  int wr = (wave >> 1) * 64, wc = (wave & 1) * 64;
  int row0 = bm * 128, col0 = bn * 128;

  int sr = tid >> 1;
  int sc = (tid & 1) * 16;
  const unsigned short* gA = X + (size_t)(row0 + sr) * K + sc;
  const unsigned short* gB = W + (size_t)(col0 + sr) * K + sc;
  unsigned short* sA = &As[sr * 40 + sc];
  unsigned short* sB = &Bs[sr * 40 + sc];

  f32x4 acc[4][4] = {};
  for (int k0 = 0; k0 < K; k0 += 32) {
    bf16x8 a0 = *(const bf16x8*)(gA + k0);
    bf16x8 a1 = *(const bf16x8*)(gA + k0 + 8);
    bf16x8 b0 = *(const bf16x8*)(gB + k0);
    bf16x8 b1 = *(const bf16x8*)(gB + k0 + 8);
    __syncthreads();
    *(bf16x8*)(sA)     = a0;
    *(bf16x8*)(sA + 8) = a1;
    *(bf16x8*)(sB)     = b0;
    *(bf16x8*)(sB + 8) = b1;
    __syncthreads();
    bf16x8 af[4], bf[4];
#pragma unroll
    for (int i = 0; i < 4; ++i) af[i] = *(const bf16x8*)&As[(wr + i*16 + lo)*40 + g*8];
#pragma unroll
    for (int i = 0; i < 4; ++i) bf[i] = *(const bf16x8*)&Bs[(wc + i*16 + lo)*40 + g*8];
#pragma unroll
    for (int mi = 0; mi < 4; ++mi)
#pragma unroll
      for (int ni = 0; ni < 4; ++ni)
        acc[mi][ni] = MFMA32(af[mi], bf[ni], acc[mi][ni]);
  }
  int orow0 = row0 + wr, ocol0 = col0 + wc;
#pragma unroll
  for (int ni = 0; ni < 4; ++ni) {
    int col = ocol0 + ni*16 + lo;
    float bc = bias[col];
#pragma unroll
    for (int mi = 0; mi < 4; ++mi) {
#pragma unroll
      for (int r = 0; r < 4; ++r) {
        int row = orow0 + mi*16 + g*4 + r;
        out[(size_t)row * 768 + col] = acc[mi][ni][r] + bc;
      }
    }
  }
}

extern "C" void kernel_launch(void* const* d_in, const int* in_sizes, int n_in,
                              void* d_out, int out_size, void* d_ws, size_t ws_size,
                              hipStream_t stream) {
  const float* x            = (const float*)d_in[0];
  const float* rel_pos_bias = (const float*)d_in[1];
  const int* mask           = (const int*)d_in[2];
  const float* Wqkv         = (const float*)d_in[3];
  const float* bqkv         = (const float*)d_in[4];
  const float* Wproj        = (const float*)d_in[5];
  const float* bproj        = (const float*)d_in[6];

  float* out0 = (float*)d_out;                         // [8,1024,768]
  float* out1 = out0 + (size_t)8 * 1024 * 768;         // [8,12,1024,1024]

  char* ws = (char*)d_ws;
  unsigned short* xb  = (unsigned short*)(ws);                 // dead after gemm_qkv
  unsigned short* wqb = (unsigned short*)(ws + 12582912);
  unsigned short* wpb = (unsigned short*)(ws + 16121856);
  unsigned short* Qb  = (unsigned short*)(ws + 17301504);
  unsigned short* Kb  = (unsigned short*)(ws + 29884416);
  unsigned short* Vb  = (unsigned short*)(ws + 42467328);
  unsigned short* ctx = (unsigned short*)(ws + 55050240);
  unsigned short* Vtb = xb;                                    // reuse xb for V^T

  cvt_all<<<8448, 256, 0, stream>>>(x, Wqkv, Wproj, xb);

  gemm_qkv<<<1152, 256, 0, stream>>>(xb, wqb, bqkv, Qb, Kb, Vb);

  vtrans<<<dim3(16, 96), 256, 0, stream>>>(Vb, Vtb);

  attn_kernel<<<dim3(16, 96), 256, 0, stream>>>(Qb, Kb, Vtb, rel_pos_bias, mask,
                                                out1, ctx);

  gemm_proj<<<384, 256, 0, stream>>>(ctx, wpb, bproj, out0);
}

// Round 6
// 243.120 us; speedup vs baseline: 2.3216x; 1.8779x over previous
//
#include <hip/hip_runtime.h>
#include <hip/hip_bf16.h>

typedef __attribute__((ext_vector_type(8))) short bf16x8;
typedef __attribute__((ext_vector_type(4))) short bf16x4;
typedef __attribute__((ext_vector_type(4))) float f32x4;

#define MFMA32(a,b,c) __builtin_amdgcn_mfma_f32_16x16x32_bf16(a,b,c,0,0,0)

#if __has_builtin(__builtin_amdgcn_mfma_f32_16x16x16bf16_1k)
#define MFMA16(a,b,c) __builtin_amdgcn_mfma_f32_16x16x16bf16_1k(a,b,c,0,0,0)
#else
static __device__ __forceinline__ f32x4 mfma16_asm(bf16x4 a, bf16x4 b, f32x4 c){
  asm volatile("v_mfma_f32_16x16x16_bf16 %0, %1, %2, %0" : "+v"(c) : "v"(a), "v"(b));
  return c;
}
#define MFMA16(a,b,c) mfma16_asm(a,b,c)
#endif

#define NEGV -65504.0f

__device__ __forceinline__ unsigned short f2bf(float f){
  union { float f; unsigned u; } x; x.f = f;
  unsigned r = x.u + 0x7fffu + ((x.u >> 16) & 1u);
  return (unsigned short)(r >> 16);
}

__device__ __forceinline__ unsigned cvtpk(float a, float b){
  unsigned r;
  asm volatile("v_cvt_pk_bf16_f32 %0, %1, %2" : "=v"(r) : "v"(a), "v"(b));
  return r;   // a -> low 16, b -> high 16
}

// ---------------- fused fp32 -> bf16 convert for x, W_qkv, W_proj ----------------
__global__ void cvt_all(const float* __restrict__ x, const float* __restrict__ wq,
                        const float* __restrict__ wp, unsigned short* __restrict__ out){
  int i = blockIdx.x * 256 + threadIdx.x;
  const float* src; int j;
  if (i < 1572864)      { src = x;  j = i; }
  else if (i < 2015232) { src = wq; j = i - 1572864; }
  else                  { src = wp; j = i - 2015232; }
  float4 f = ((const float4*)src)[j];
  ushort4 u;
  u.x = f2bf(f.x); u.y = f2bf(f.y); u.z = f2bf(f.z); u.w = f2bf(f.w);
  ((ushort4*)out)[i] = u;
}

// ---------------- mask int32 -> bitmask (1 bit per element) ----------------
// out: [8*1024 rows][16 u64 words]  (1 MB total)
__global__ __launch_bounds__(256) void mask_to_bits(const int* __restrict__ m,
                                                    unsigned long long* __restrict__ out){
  int gw = (blockIdx.x * 256 + threadIdx.x) >> 6;   // global wave id 0..8191
  int lane = threadIdx.x & 63;
#pragma unroll
  for (int stp = 0; stp < 16; ++stp) {
    size_t base = ((size_t)gw * 16 + stp) * 64;
    int v = m[base + lane];
    unsigned long long bb = __ballot(v != 0);
    if (lane == 0) out[base >> 6] = bb;
  }
}

// ---------------- LDS-staged QKV GEMM: X[8192,768] @ W[2304,768]^T + b ----------
__global__ __launch_bounds__(256) void gemm_qkv(
    const unsigned short* __restrict__ X,
    const unsigned short* __restrict__ W,
    const float* __restrict__ bias,
    unsigned short* __restrict__ Qd,
    unsigned short* __restrict__ Kd,
    unsigned short* __restrict__ Vd)
{
  __shared__ unsigned short As[128*40];
  __shared__ unsigned short Bs[128*40];
  const int K = 768;
  int tid = threadIdx.x;
  int bm = blockIdx.x & 63;
  int bn = blockIdx.x >> 6;
  int wave = tid >> 6, lane = tid & 63;
  int lo = lane & 15, g = lane >> 4;
  int wr = (wave >> 1) * 64, wc = (wave & 1) * 64;
  int row0 = bm * 128, col0 = bn * 128;

  int sr = tid >> 1;
  int sc = (tid & 1) * 16;
  const unsigned short* gA = X + (size_t)(row0 + sr) * K + sc;
  const unsigned short* gB = W + (size_t)(col0 + sr) * K + sc;
  unsigned short* sA = &As[sr * 40 + sc];
  unsigned short* sB = &Bs[sr * 40 + sc];

  f32x4 acc[4][4] = {};
  for (int k0 = 0; k0 < K; k0 += 32) {
    bf16x8 a0 = *(const bf16x8*)(gA + k0);
    bf16x8 a1 = *(const bf16x8*)(gA + k0 + 8);
    bf16x8 b0 = *(const bf16x8*)(gB + k0);
    bf16x8 b1 = *(const bf16x8*)(gB + k0 + 8);
    __syncthreads();
    *(bf16x8*)(sA)     = a0;
    *(bf16x8*)(sA + 8) = a1;
    *(bf16x8*)(sB)     = b0;
    *(bf16x8*)(sB + 8) = b1;
    __syncthreads();
    bf16x8 af[4], bf[4];
#pragma unroll
    for (int i = 0; i < 4; ++i) af[i] = *(const bf16x8*)&As[(wr + i*16 + lo)*40 + g*8];
#pragma unroll
    for (int i = 0; i < 4; ++i) bf[i] = *(const bf16x8*)&Bs[(wc + i*16 + lo)*40 + g*8];
#pragma unroll
    for (int mi = 0; mi < 4; ++mi)
#pragma unroll
      for (int ni = 0; ni < 4; ++ni)
        acc[mi][ni] = MFMA32(af[mi], bf[ni], acc[mi][ni]);
  }
  int orow0 = row0 + wr, ocol0 = col0 + wc;
#pragma unroll
  for (int ni = 0; ni < 4; ++ni) {
    int col = ocol0 + ni*16 + lo;
    float bc = bias[col];
    int which = col / 768;
    int rem = col - which * 768;
    int h = rem >> 6, d = rem & 63;
    unsigned short* dst = (which == 0) ? Qd : (which == 1) ? Kd : Vd;
    float scale = (which == 0) ? 0.125f : 1.0f;
#pragma unroll
    for (int mi = 0; mi < 4; ++mi) {
#pragma unroll
      for (int r = 0; r < 4; ++r) {
        int row = orow0 + mi*16 + g*4 + r;
        int bb = row >> 10, n = row & 1023;
        dst[(((size_t)bb*12 + h)*1024 + n)*64 + d] = f2bf((acc[mi][ni][r] + bc) * scale);
      }
    }
  }
}

// ---------------- V transpose: [96][1024][64] -> [96][64][1024] ----------------
__global__ __launch_bounds__(256) void vtrans(const unsigned short* __restrict__ V,
                                              unsigned short* __restrict__ Vt){
  __shared__ unsigned short t[64][72];
  int bh = blockIdx.y;
  int n0 = blockIdx.x * 64;
  int tid = threadIdx.x;
  int nl = tid >> 2;
  int dq = (tid & 3) * 16;
  const unsigned short* src = V + ((size_t)bh*1024 + n0 + nl)*64 + dq;
  bf16x8 a0 = *(const bf16x8*)(src);
  bf16x8 a1 = *(const bf16x8*)(src + 8);
  *(bf16x8*)&t[nl][dq]     = a0;
  *(bf16x8*)&t[nl][dq + 8] = a1;
  __syncthreads();
  int d  = tid >> 2;
  int nq = (tid & 3) * 16;
  union { unsigned short s[16]; bf16x8 v[2]; } pk;
#pragma unroll
  for (int j = 0; j < 16; ++j) pk.s[j] = t[nq + j][d];
  unsigned short* dst = Vt + ((size_t)bh*64 + d)*1024 + n0 + nq;
  *(bf16x8*)(dst)     = pk.v[0];
  *(bf16x8*)(dst + 8) = pk.v[1];
}

// ---------------- fused attention core, 8 waves, LDS-shared K/V ----------------
// grid (8 qblocks, 96); block 512 = 8 waves x 16 q-rows; KVBLK=64 double-buffered.
// LDS layout: [K0 8K][K1 8K][V0 8K][V1 8K]; XOR swizzle byte^=((row&7)<<4),
// applied as inverse-swizzled global_load_lds source + swizzled ds_read (rule #21).
__global__ __launch_bounds__(512, 4) void attn_kernel(
    const unsigned short* __restrict__ Qd,
    const unsigned short* __restrict__ Kd,
    const unsigned short* __restrict__ Vt,     // [96][64][1024]
    const float* __restrict__ bias,            // [12,1024,1024] fp32
    const unsigned* __restrict__ maskbits,     // [8*1024][32] u32 words
    float* __restrict__ out1,                  // [96,1024,1024] fp32
    unsigned short* __restrict__ ctx)          // [8192,768] bf16
{
  __shared__ char lds[32768];
  const int N = 1024, D = 64;
  int y = blockIdx.y;
  int h = y >> 3, bb = y & 7;
  int bh = bb * 12 + h;
  int tid = threadIdx.x;
  int wave = tid >> 6, lane = tid & 63;
  int lo = lane & 15, g = lane >> 4;
  int qrow = blockIdx.x * 128 + wave * 16 + lo;

  const size_t qoff = ((size_t)bh * N + qrow) * D;
  bf16x8 qf0 = *(const bf16x8*)(Qd + qoff + g*8);
  bf16x8 qf1 = *(const bf16x8*)(Qd + qoff + 32 + g*8);

  const float* bias_row = bias + ((size_t)h * N + qrow) * N;
  const unsigned* mrow  = maskbits + ((size_t)bb * N + qrow) * 32;
  float* out_row        = out1 + ((size_t)bh * N + qrow) * N;

  // staging: thread t fills lds byte o=t*16; content = tile[swz(o)] so that
  // reading phys=swz(logical) returns tile[logical].
  int o  = tid * 16;
  int sw = o ^ (((o >> 7) & 7) << 4);
  const char* kbase = (const char*)(Kd + (size_t)bh * N * D);
  const char* vbase = (const char*)(Vt + (size_t)bh * D * N);
  const char* ksrc  = kbase + sw;                           // + kv*128 per tile
  const char* vsrc  = vbase + (o >> 7) * 2048 + (sw & 127); // + kv*2 per tile
  int wbase = (tid >> 6) << 10;                             // wave-uniform LDS base

#define STAGE(buf, kv) do { \
    __builtin_amdgcn_global_load_lds( \
      (const __attribute__((address_space(1))) unsigned*)(ksrc + (size_t)(kv)*128), \
      (__attribute__((address_space(3))) unsigned*)(lds + (buf)*8192 + wbase), 16, 0, 0); \
    __builtin_amdgcn_global_load_lds( \
      (const __attribute__((address_space(1))) unsigned*)(vsrc + (size_t)(kv)*2), \
      (__attribute__((address_space(3))) unsigned*)(lds + 16384 + (buf)*8192 + wbase), 16, 0, 0); \
  } while (0)

#define SWZ(lb) ((lb) ^ ((((lb) >> 7) & 7) << 4))

  float m_run = -INFINITY, l_part = 0.0f;
  f32x4 oacc[4] = {};   // O^T: lane holds q=lo, d = c*16 + g*4 + reg

  STAGE(0, 0);
  __syncthreads();
  int cur = 0;

  for (int it = 0; it < 16; ++it) {
    int kv = it * 64;
    if (it < 15) STAGE(cur ^ 1, kv + 64);

    unsigned mw0 = mrow[it*2];
    unsigned mw1 = mrow[it*2 + 1];

    // QK^T over 4 sub-tiles of 16 kpos: s[sub][r] = S[q=lo][kv + sub*16 + g*4 + r]
    f32x4 s[4];
#pragma unroll
    for (int sub = 0; sub < 4; ++sub) {
      int lbr = (sub*16 + lo) * 128 + g*16;
      bf16x8 k0 = *(const bf16x8*)(lds + cur*8192 + SWZ(lbr));
      bf16x8 k1 = *(const bf16x8*)(lds + cur*8192 + SWZ(lbr + 64));
      f32x4 t = {};
      t = MFMA32(k0, qf0, t);
      t = MFMA32(k1, qf1, t);
      s[sub] = t;
    }

    // mask (bits) + bias + out1 dump
    float sp[16];
#pragma unroll
    for (int sub = 0; sub < 4; ++sub) {
      f32x4 bi = *(const f32x4*)(bias_row + kv + sub*16 + g*4);
      unsigned mw = (sub < 2) ? mw0 : mw1;
      int sh = (sub & 1) * 16 + g * 4;
#pragma unroll
      for (int r = 0; r < 4; ++r)
        sp[sub*4+r] = (((mw >> (sh + r)) & 1u) ? NEGV : s[sub][r]) + bi[r];
      f32x4 ov;
      ov[0] = sp[sub*4]; ov[1] = sp[sub*4+1]; ov[2] = sp[sub*4+2]; ov[3] = sp[sub*4+3];
      __builtin_nontemporal_store(ov, (f32x4*)(out_row + kv + sub*16 + g*4));
    }

    // deferred-max online softmax
    float lmax = sp[0];
#pragma unroll
    for (int i = 1; i < 16; ++i) lmax = fmaxf(lmax, sp[i]);
    if (!__all(lmax <= m_run + 8.0f)) {
      float tmax = fmaxf(lmax, __shfl_xor(lmax, 16));
      tmax = fmaxf(tmax, __shfl_xor(tmax, 32));
      float mnew = fmaxf(m_run, tmax);
      float alpha = __expf(m_run - mnew);
      l_part *= alpha;
#pragma unroll
      for (int c = 0; c < 4; ++c) {
        oacc[c][0] *= alpha; oacc[c][1] *= alpha;
        oacc[c][2] *= alpha; oacc[c][3] *= alpha;
      }
      m_run = mnew;
    }
    float lsum = 0.0f;
#pragma unroll
    for (int i = 0; i < 16; ++i) { sp[i] = __expf(sp[i] - m_run); lsum += sp[i]; }
    l_part += lsum;

    union { unsigned u[2]; bf16x4 h; } pk[4];
#pragma unroll
    for (int ks = 0; ks < 4; ++ks) {
      pk[ks].u[0] = cvtpk(sp[ks*4],   sp[ks*4+1]);
      pk[ks].u[1] = cvtpk(sp[ks*4+2], sp[ks*4+3]);
    }

    // PV: oacc[c] += Vs[d=c*16+lo][k=ks*16+g*4+e] x P
#pragma unroll
    for (int ks = 0; ks < 4; ++ks)
#pragma unroll
      for (int c = 0; c < 4; ++c) {
        int lbv = (c*16 + lo) * 128 + ks*32 + g*8;
        bf16x4 vf = *(const bf16x4*)(lds + 16384 + cur*8192 + SWZ(lbv));
        oacc[c] = MFMA16(vf, pk[ks].h, oacc[c]);
      }

    cur ^= 1;
    __syncthreads();   // drains staged loads; all waves done reading old buffer
  }

  l_part += __shfl_xor(l_part, 16);
  l_part += __shfl_xor(l_part, 32);
  float inv = 1.0f / l_part;

  size_t crow = ((size_t)bb * N + qrow) * 768 + h * 64;
#pragma unroll
  for (int c = 0; c < 4; ++c) {
    ushort4 u;
    u.x = f2bf(oacc[c][0] * inv);
    u.y = f2bf(oacc[c][1] * inv);
    u.z = f2bf(oacc[c][2] * inv);
    u.w = f2bf(oacc[c][3] * inv);
    *(ushort4*)(ctx + crow + c*16 + g*4) = u;
  }
#undef STAGE
#undef SWZ
}

// ---------------- LDS-staged proj GEMM: ctx[8192,768] @ Wp[768,768]^T + b ------
__global__ __launch_bounds__(256) void gemm_proj(
    const unsigned short* __restrict__ X,
    const unsigned short* __restrict__ W,
    const float* __restrict__ bias,
    float* __restrict__ out)
{
  __shared__ unsigned short As[128*40];
  __shared__ unsigned short Bs[128*40];
  const int K = 768;
  int tid = threadIdx.x;
  int bm = blockIdx.x & 63;
  int bn = blockIdx.x >> 6;
  int wave = tid >> 6, lane = tid & 63;
  int lo = lane & 15, g = lane >> 4;
  int wr = (wave >> 1) * 64, wc = (wave & 1) * 64;
  int row0 = bm * 128, col0 = bn * 128;

  int sr = tid >> 1;
  int sc = (tid & 1) * 16;
  const unsigned short* gA = X + (size_t)(row0 + sr) * K + sc;
  const unsigned short* gB = W + (size_t)(col0 + sr) * K + sc;
  unsigned short* sA = &As[sr * 40 + sc];
  unsigned short* sB = &Bs[sr * 40 + sc];

  f32x4 acc[4][4] = {};
  for (int k0 = 0; k0 < K; k0 += 32) {
    bf16x8 a0 = *(const bf16x8*)(gA + k0);
    bf16x8 a1 = *(const bf16x8*)(gA + k0 + 8);
    bf16x8 b0 = *(const bf16x8*)(gB + k0);
    bf16x8 b1 = *(const bf16x8*)(gB + k0 + 8);
    __syncthreads();
    *(bf16x8*)(sA)     = a0;
    *(bf16x8*)(sA + 8) = a1;
    *(bf16x8*)(sB)     = b0;
    *(bf16x8*)(sB + 8) = b1;
    __syncthreads();
    bf16x8 af[4], bf[4];
#pragma unroll
    for (int i = 0; i < 4; ++i) af[i] = *(const bf16x8*)&As[(wr + i*16 + lo)*40 + g*8];
#pragma unroll
    for (int i = 0; i < 4; ++i) bf[i] = *(const bf16x8*)&Bs[(wc + i*16 + lo)*40 + g*8];
#pragma unroll
    for (int mi = 0; mi < 4; ++mi)
#pragma unroll
      for (int ni = 0; ni < 4; ++ni)
        acc[mi][ni] = MFMA32(af[mi], bf[ni], acc[mi][ni]);
  }
  int orow0 = row0 + wr, ocol0 = col0 + wc;
#pragma unroll
  for (int ni = 0; ni < 4; ++ni) {
    int col = ocol0 + ni*16 + lo;
    float bc = bias[col];
#pragma unroll
    for (int mi = 0; mi < 4; ++mi) {
#pragma unroll
      for (int r = 0; r < 4; ++r) {
        int row = orow0 + mi*16 + g*4 + r;
        out[(size_t)row * 768 + col] = acc[mi][ni][r] + bc;
      }
    }
  }
}

extern "C" void kernel_launch(void* const* d_in, const int* in_sizes, int n_in,
                              void* d_out, int out_size, void* d_ws, size_t ws_size,
                              hipStream_t stream) {
  const float* x            = (const float*)d_in[0];
  const float* rel_pos_bias = (const float*)d_in[1];
  const int* mask           = (const int*)d_in[2];
  const float* Wqkv         = (const float*)d_in[3];
  const float* bqkv         = (const float*)d_in[4];
  const float* Wproj        = (const float*)d_in[5];
  const float* bproj        = (const float*)d_in[6];

  float* out0 = (float*)d_out;                         // [8,1024,768]
  float* out1 = out0 + (size_t)8 * 1024 * 768;         // [8,12,1024,1024]

  char* ws = (char*)d_ws;
  unsigned short* xb  = (unsigned short*)(ws);            // dead after gemm_qkv -> Vt
  unsigned short* wqb = (unsigned short*)(ws + 12582912); // dead after gemm_qkv -> maskbits
  unsigned short* wpb = (unsigned short*)(ws + 16121856);
  unsigned short* Qb  = (unsigned short*)(ws + 17301504);
  unsigned short* Kb  = (unsigned short*)(ws + 29884416);
  unsigned short* Vb  = (unsigned short*)(ws + 42467328);
  unsigned short* ctx = (unsigned short*)(ws + 55050240);
  unsigned short* Vtb = xb;
  unsigned long long* mbits = (unsigned long long*)(ws + 12582912);

  cvt_all<<<8448, 256, 0, stream>>>(x, Wqkv, Wproj, xb);

  gemm_qkv<<<1152, 256, 0, stream>>>(xb, wqb, bqkv, Qb, Kb, Vb);

  mask_to_bits<<<2048, 256, 0, stream>>>(mask, mbits);

  vtrans<<<dim3(16, 96), 256, 0, stream>>>(Vb, Vtb);

  attn_kernel<<<dim3(8, 96), 512, 0, stream>>>(Qb, Kb, Vtb, rel_pos_bias,
                                               (const unsigned*)mbits, out1, ctx);

  gemm_proj<<<384, 256, 0, stream>>>(ctx, wpb, bproj, out0);
}

// Round 7
// 233.991 us; speedup vs baseline: 2.4122x; 1.0390x over previous
//
#include <hip/hip_runtime.h>
#include <hip/hip_bf16.h>

typedef __attribute__((ext_vector_type(8))) short bf16x8;
typedef __attribute__((ext_vector_type(4))) short bf16x4;
typedef __attribute__((ext_vector_type(4))) float f32x4;

#define MFMA32(a,b,c) __builtin_amdgcn_mfma_f32_16x16x32_bf16(a,b,c,0,0,0)

#if __has_builtin(__builtin_amdgcn_mfma_f32_16x16x16bf16_1k)
#define MFMA16(a,b,c) __builtin_amdgcn_mfma_f32_16x16x16bf16_1k(a,b,c,0,0,0)
#else
static __device__ __forceinline__ f32x4 mfma16_asm(bf16x4 a, bf16x4 b, f32x4 c){
  asm volatile("v_mfma_f32_16x16x16_bf16 %0, %1, %2, %0" : "+v"(c) : "v"(a), "v"(b));
  return c;
}
#define MFMA16(a,b,c) mfma16_asm(a,b,c)
#endif

#define NEGV -65504.0f

__device__ __forceinline__ unsigned short f2bf(float f){
  union { float f; unsigned u; } x; x.f = f;
  unsigned r = x.u + 0x7fffu + ((x.u >> 16) & 1u);
  return (unsigned short)(r >> 16);
}

__device__ __forceinline__ unsigned cvtpk(float a, float b){
  unsigned r;
  asm volatile("v_cvt_pk_bf16_f32 %0, %1, %2" : "=v"(r) : "v"(a), "v"(b));
  return r;   // a -> low 16, b -> high 16
}

// ---------------- fused fp32 -> bf16 convert for x, W_qkv, W_proj ----------------
__global__ void cvt_all(const float* __restrict__ x, const float* __restrict__ wq,
                        const float* __restrict__ wp, unsigned short* __restrict__ out){
  int i = blockIdx.x * 256 + threadIdx.x;
  const float* src; int j;
  if (i < 1572864)      { src = x;  j = i; }
  else if (i < 2015232) { src = wq; j = i - 1572864; }
  else                  { src = wp; j = i - 2015232; }
  float4 f = ((const float4*)src)[j];
  ushort4 u;
  u.x = f2bf(f.x); u.y = f2bf(f.y); u.z = f2bf(f.z); u.w = f2bf(f.w);
  ((ushort4*)out)[i] = u;
}

// ---------------- mask int32 -> bitmask (1 bit per element) ----------------
__global__ __launch_bounds__(256) void mask_to_bits(const int* __restrict__ m,
                                                    unsigned long long* __restrict__ out){
  int gw = (blockIdx.x * 256 + threadIdx.x) >> 6;
  int lane = threadIdx.x & 63;
#pragma unroll
  for (int stp = 0; stp < 16; ++stp) {
    size_t base = ((size_t)gw * 16 + stp) * 64;
    int v = m[base + lane];
    unsigned long long bb = __ballot(v != 0);
    if (lane == 0) out[base >> 6] = bb;
  }
}

// ---------------- LDS-staged QKV GEMM: X[8192,768] @ W[2304,768]^T + b ----------
__global__ __launch_bounds__(256) void gemm_qkv(
    const unsigned short* __restrict__ X,
    const unsigned short* __restrict__ W,
    const float* __restrict__ bias,
    unsigned short* __restrict__ Qd,
    unsigned short* __restrict__ Kd,
    unsigned short* __restrict__ Vd)
{
  __shared__ unsigned short As[128*40];
  __shared__ unsigned short Bs[128*40];
  const int K = 768;
  int tid = threadIdx.x;
  int bm = blockIdx.x & 63;
  int bn = blockIdx.x >> 6;
  int wave = tid >> 6, lane = tid & 63;
  int lo = lane & 15, g = lane >> 4;
  int wr = (wave >> 1) * 64, wc = (wave & 1) * 64;
  int row0 = bm * 128, col0 = bn * 128;

  int sr = tid >> 1;
  int sc = (tid & 1) * 16;
  const unsigned short* gA = X + (size_t)(row0 + sr) * K + sc;
  const unsigned short* gB = W + (size_t)(col0 + sr) * K + sc;
  unsigned short* sA = &As[sr * 40 + sc];
  unsigned short* sB = &Bs[sr * 40 + sc];

  f32x4 acc[4][4] = {};
  for (int k0 = 0; k0 < K; k0 += 32) {
    bf16x8 a0 = *(const bf16x8*)(gA + k0);
    bf16x8 a1 = *(const bf16x8*)(gA + k0 + 8);
    bf16x8 b0 = *(const bf16x8*)(gB + k0);
    bf16x8 b1 = *(const bf16x8*)(gB + k0 + 8);
    __syncthreads();
    *(bf16x8*)(sA)     = a0;
    *(bf16x8*)(sA + 8) = a1;
    *(bf16x8*)(sB)     = b0;
    *(bf16x8*)(sB + 8) = b1;
    __syncthreads();
    bf16x8 af[4], bf[4];
#pragma unroll
    for (int i = 0; i < 4; ++i) af[i] = *(const bf16x8*)&As[(wr + i*16 + lo)*40 + g*8];
#pragma unroll
    for (int i = 0; i < 4; ++i) bf[i] = *(const bf16x8*)&Bs[(wc + i*16 + lo)*40 + g*8];
#pragma unroll
    for (int mi = 0; mi < 4; ++mi)
#pragma unroll
      for (int ni = 0; ni < 4; ++ni)
        acc[mi][ni] = MFMA32(af[mi], bf[ni], acc[mi][ni]);
  }
  int orow0 = row0 + wr, ocol0 = col0 + wc;
#pragma unroll
  for (int ni = 0; ni < 4; ++ni) {
    int col = ocol0 + ni*16 + lo;
    float bc = bias[col];
    int which = col / 768;
    int rem = col - which * 768;
    int h = rem >> 6, d = rem & 63;
    unsigned short* dst = (which == 0) ? Qd : (which == 1) ? Kd : Vd;
    float scale = (which == 0) ? 0.125f : 1.0f;
#pragma unroll
    for (int mi = 0; mi < 4; ++mi) {
#pragma unroll
      for (int r = 0; r < 4; ++r) {
        int row = orow0 + mi*16 + g*4 + r;
        int bb = row >> 10, n = row & 1023;
        dst[(((size_t)bb*12 + h)*1024 + n)*64 + d] = f2bf((acc[mi][ni][r] + bc) * scale);
      }
    }
  }
}

// ---------------- V transpose: [96][1024][64] -> [96][64][1024] ----------------
__global__ __launch_bounds__(256) void vtrans(const unsigned short* __restrict__ V,
                                              unsigned short* __restrict__ Vt){
  __shared__ unsigned short t[64][72];
  int bh = blockIdx.y;
  int n0 = blockIdx.x * 64;
  int tid = threadIdx.x;
  int nl = tid >> 2;
  int dq = (tid & 3) * 16;
  const unsigned short* src = V + ((size_t)bh*1024 + n0 + nl)*64 + dq;
  bf16x8 a0 = *(const bf16x8*)(src);
  bf16x8 a1 = *(const bf16x8*)(src + 8);
  *(bf16x8*)&t[nl][dq]     = a0;
  *(bf16x8*)&t[nl][dq + 8] = a1;
  __syncthreads();
  int d  = tid >> 2;
  int nq = (tid & 3) * 16;
  union { unsigned short s[16]; bf16x8 v[2]; } pk;
#pragma unroll
  for (int j = 0; j < 16; ++j) pk.s[j] = t[nq + j][d];
  unsigned short* dst = Vt + ((size_t)bh*64 + d)*1024 + n0 + nq;
  *(bf16x8*)(dst)     = pk.v[0];
  *(bf16x8*)(dst + 8) = pk.v[1];
}

// ---------------- fused attention core, 8 waves, LDS-shared K/V ----------------
// grid (8 qblocks, 96); block 512 = 8 waves x 16 q-rows; KVBLK=64 double-buffered.
// Counted-vmcnt barrier: only staged loads must retire; NT out1 stores drift
// across the barrier (T4). setprio around MFMA clusters (T5).
__global__ __launch_bounds__(512, 4) void attn_kernel(
    const unsigned short* __restrict__ Qd,
    const unsigned short* __restrict__ Kd,
    const unsigned short* __restrict__ Vt,     // [96][64][1024]
    const float* __restrict__ bias,            // [12,1024,1024] fp32
    const unsigned* __restrict__ maskbits,     // [8*1024][32] u32 words
    float* __restrict__ out1,                  // [96,1024,1024] fp32
    unsigned short* __restrict__ ctx)          // [8192,768] bf16
{
  __shared__ char lds[32768];
  const int N = 1024, D = 64;
  int y = blockIdx.y;
  int h = y >> 3, bb = y & 7;
  int bh = bb * 12 + h;
  int tid = threadIdx.x;
  int wave = tid >> 6, lane = tid & 63;
  int lo = lane & 15, g = lane >> 4;
  int qrow = blockIdx.x * 128 + wave * 16 + lo;

  const size_t qoff = ((size_t)bh * N + qrow) * D;
  bf16x8 qf0 = *(const bf16x8*)(Qd + qoff + g*8);
  bf16x8 qf1 = *(const bf16x8*)(Qd + qoff + 32 + g*8);

  const float* bias_row = bias + ((size_t)h * N + qrow) * N;
  const unsigned* mrow  = maskbits + ((size_t)bb * N + qrow) * 32;
  float* out_row        = out1 + ((size_t)bh * N + qrow) * N;

  // staging: thread t fills lds byte o=t*16; content = tile[swz(o)] so that
  // reading phys=swz(logical) returns tile[logical].
  int o  = tid * 16;
  int sw = o ^ (((o >> 7) & 7) << 4);
  const char* kbase = (const char*)(Kd + (size_t)bh * N * D);
  const char* vbase = (const char*)(Vt + (size_t)bh * D * N);
  const char* ksrc  = kbase + sw;                           // + kv*128 per tile
  const char* vsrc  = vbase + (o >> 7) * 2048 + (sw & 127); // + kv*2 per tile
  int wbase = (tid >> 6) << 10;                             // wave-uniform LDS base

#define STAGE(buf, kv) do { \
    __builtin_amdgcn_global_load_lds( \
      (const __attribute__((address_space(1))) unsigned*)(ksrc + (size_t)(kv)*128), \
      (__attribute__((address_space(3))) unsigned*)(lds + (buf)*8192 + wbase), 16, 0, 0); \
    __builtin_amdgcn_global_load_lds( \
      (const __attribute__((address_space(1))) unsigned*)(vsrc + (size_t)(kv)*2), \
      (__attribute__((address_space(3))) unsigned*)(lds + 16384 + (buf)*8192 + wbase), 16, 0, 0); \
  } while (0)

#define SWZ(lb) ((lb) ^ ((((lb) >> 7) & 7) << 4))

  float m_run = -INFINITY, l_part = 0.0f;
  f32x4 oacc[4] = {};   // O^T: lane holds q=lo, d = c*16 + g*4 + reg

  STAGE(0, 0);
  __syncthreads();      // prologue: full drain (no stores outstanding yet)
  int cur = 0;

  for (int it = 0; it < 16; ++it) {
    int kv = it * 64;
    // STAGE first so the staged loads are the OLDEST vmem ops of this iter
    if (it < 15) STAGE(cur ^ 1, kv + 64);
    __builtin_amdgcn_sched_barrier(0);   // pin: stage stays oldest

    unsigned mw0 = mrow[it*2];
    unsigned mw1 = mrow[it*2 + 1];

    // QK^T over 4 sub-tiles of 16 kpos: s[sub][r] = S[q=lo][kv + sub*16 + g*4 + r]
    f32x4 s[4];
    __builtin_amdgcn_s_setprio(1);
#pragma unroll
    for (int sub = 0; sub < 4; ++sub) {
      int lbr = (sub*16 + lo) * 128 + g*16;
      bf16x8 k0 = *(const bf16x8*)(lds + cur*8192 + SWZ(lbr));
      bf16x8 k1 = *(const bf16x8*)(lds + cur*8192 + SWZ(lbr + 64));
      f32x4 t = {};
      t = MFMA32(k0, qf0, t);
      t = MFMA32(k1, qf1, t);
      s[sub] = t;
    }
    __builtin_amdgcn_s_setprio(0);

    // mask (bits) + bias + out1 dump
    float sp[16];
#pragma unroll
    for (int sub = 0; sub < 4; ++sub) {
      f32x4 bi = *(const f32x4*)(bias_row + kv + sub*16 + g*4);
      unsigned mw = (sub < 2) ? mw0 : mw1;
      int sh = (sub & 1) * 16 + g * 4;
#pragma unroll
      for (int r = 0; r < 4; ++r)
        sp[sub*4+r] = (((mw >> (sh + r)) & 1u) ? NEGV : s[sub][r]) + bi[r];
      f32x4 ov;
      ov[0] = sp[sub*4]; ov[1] = sp[sub*4+1]; ov[2] = sp[sub*4+2]; ov[3] = sp[sub*4+3];
      __builtin_nontemporal_store(ov, (f32x4*)(out_row + kv + sub*16 + g*4));
    }

    // deferred-max online softmax
    float lmax = sp[0];
#pragma unroll
    for (int i = 1; i < 16; ++i) lmax = fmaxf(lmax, sp[i]);
    if (!__all(lmax <= m_run + 8.0f)) {
      float tmax = fmaxf(lmax, __shfl_xor(lmax, 16));
      tmax = fmaxf(tmax, __shfl_xor(tmax, 32));
      float mnew = fmaxf(m_run, tmax);
      float alpha = __expf(m_run - mnew);
      l_part *= alpha;
#pragma unroll
      for (int c = 0; c < 4; ++c) {
        oacc[c][0] *= alpha; oacc[c][1] *= alpha;
        oacc[c][2] *= alpha; oacc[c][3] *= alpha;
      }
      m_run = mnew;
    }
    float lsum = 0.0f;
#pragma unroll
    for (int i = 0; i < 16; ++i) { sp[i] = __expf(sp[i] - m_run); lsum += sp[i]; }
    l_part += lsum;

    union { unsigned u[2]; bf16x4 h; } pk[4];
#pragma unroll
    for (int ks = 0; ks < 4; ++ks) {
      pk[ks].u[0] = cvtpk(sp[ks*4],   sp[ks*4+1]);
      pk[ks].u[1] = cvtpk(sp[ks*4+2], sp[ks*4+3]);
    }

    // PV: oacc[c] += Vs[d=c*16+lo][k=ks*16+g*4+e] x P
    __builtin_amdgcn_s_setprio(1);
#pragma unroll
    for (int ks = 0; ks < 4; ++ks)
#pragma unroll
      for (int c = 0; c < 4; ++c) {
        int lbv = (c*16 + lo) * 128 + ks*32 + g*8;
        bf16x4 vf = *(const bf16x4*)(lds + 16384 + cur*8192 + SWZ(lbv));
        oacc[c] = MFMA16(vf, pk[ks].h, oacc[c]);
      }
    __builtin_amdgcn_s_setprio(0);

    cur ^= 1;
    // counted barrier: retire everything except the <=4 newest (the NT stores).
    // Staged loads are oldest -> guaranteed retired; lgkm drained by MFMA use.
    __builtin_amdgcn_sched_barrier(0);
    asm volatile("s_waitcnt vmcnt(4)" ::: "memory");
    __builtin_amdgcn_s_barrier();
  }

  l_part += __shfl_xor(l_part, 16);
  l_part += __shfl_xor(l_part, 32);
  float inv = 1.0f / l_part;

  size_t crow = ((size_t)bb * N + qrow) * 768 + h * 64;
#pragma unroll
  for (int c = 0; c < 4; ++c) {
    ushort4 u;
    u.x = f2bf(oacc[c][0] * inv);
    u.y = f2bf(oacc[c][1] * inv);
    u.z = f2bf(oacc[c][2] * inv);
    u.w = f2bf(oacc[c][3] * inv);
    *(ushort4*)(ctx + crow + c*16 + g*4) = u;
  }
#undef STAGE
#undef SWZ
}

// ---------------- LDS-staged proj GEMM: ctx[8192,768] @ Wp[768,768]^T + b ------
__global__ __launch_bounds__(256) void gemm_proj(
    const unsigned short* __restrict__ X,
    const unsigned short* __restrict__ W,
    const float* __restrict__ bias,
    float* __restrict__ out)
{
  __shared__ unsigned short As[128*40];
  __shared__ unsigned short Bs[128*40];
  const int K = 768;
  int tid = threadIdx.x;
  int bm = blockIdx.x & 63;
  int bn = blockIdx.x >> 6;
  int wave = tid >> 6, lane = tid & 63;
  int lo = lane & 15, g = lane >> 4;
  int wr = (wave >> 1) * 64, wc = (wave & 1) * 64;
  int row0 = bm * 128, col0 = bn * 128;

  int sr = tid >> 1;
  int sc = (tid & 1) * 16;
  const unsigned short* gA = X + (size_t)(row0 + sr) * K + sc;
  const unsigned short* gB = W + (size_t)(col0 + sr) * K + sc;
  unsigned short* sA = &As[sr * 40 + sc];
  unsigned short* sB = &Bs[sr * 40 + sc];

  f32x4 acc[4][4] = {};
  for (int k0 = 0; k0 < K; k0 += 32) {
    bf16x8 a0 = *(const bf16x8*)(gA + k0);
    bf16x8 a1 = *(const bf16x8*)(gA + k0 + 8);
    bf16x8 b0 = *(const bf16x8*)(gB + k0);
    bf16x8 b1 = *(const bf16x8*)(gB + k0 + 8);
    __syncthreads();
    *(bf16x8*)(sA)     = a0;
    *(bf16x8*)(sA + 8) = a1;
    *(bf16x8*)(sB)     = b0;
    *(bf16x8*)(sB + 8) = b1;
    __syncthreads();
    bf16x8 af[4], bf[4];
#pragma unroll
    for (int i = 0; i < 4; ++i) af[i] = *(const bf16x8*)&As[(wr + i*16 + lo)*40 + g*8];
#pragma unroll
    for (int i = 0; i < 4; ++i) bf[i] = *(const bf16x8*)&Bs[(wc + i*16 + lo)*40 + g*8];
#pragma unroll
    for (int mi = 0; mi < 4; ++mi)
#pragma unroll
      for (int ni = 0; ni < 4; ++ni)
        acc[mi][ni] = MFMA32(af[mi], bf[ni], acc[mi][ni]);
  }
  int orow0 = row0 + wr, ocol0 = col0 + wc;
#pragma unroll
  for (int ni = 0; ni < 4; ++ni) {
    int col = ocol0 + ni*16 + lo;
    float bc = bias[col];
#pragma unroll
    for (int mi = 0; mi < 4; ++mi) {
#pragma unroll
      for (int r = 0; r < 4; ++r) {
        int row = orow0 + mi*16 + g*4 + r;
        out[(size_t)row * 768 + col] = acc[mi][ni][r] + bc;
      }
    }
  }
}

extern "C" void kernel_launch(void* const* d_in, const int* in_sizes, int n_in,
                              void* d_out, int out_size, void* d_ws, size_t ws_size,
                              hipStream_t stream) {
  const float* x            = (const float*)d_in[0];
  const float* rel_pos_bias = (const float*)d_in[1];
  const int* mask           = (const int*)d_in[2];
  const float* Wqkv         = (const float*)d_in[3];
  const float* bqkv         = (const float*)d_in[4];
  const float* Wproj        = (const float*)d_in[5];
  const float* bproj        = (const float*)d_in[6];

  float* out0 = (float*)d_out;                         // [8,1024,768]
  float* out1 = out0 + (size_t)8 * 1024 * 768;         // [8,12,1024,1024]

  char* ws = (char*)d_ws;
  unsigned short* xb  = (unsigned short*)(ws);            // dead after gemm_qkv -> Vt
  unsigned short* wqb = (unsigned short*)(ws + 12582912); // dead after gemm_qkv -> maskbits
  unsigned short* wpb = (unsigned short*)(ws + 16121856);
  unsigned short* Qb  = (unsigned short*)(ws + 17301504);
  unsigned short* Kb  = (unsigned short*)(ws + 29884416);
  unsigned short* Vb  = (unsigned short*)(ws + 42467328);
  unsigned short* ctx = (unsigned short*)(ws + 55050240);
  unsigned short* Vtb = xb;
  unsigned long long* mbits = (unsigned long long*)(ws + 12582912);

  cvt_all<<<8448, 256, 0, stream>>>(x, Wqkv, Wproj, xb);

  gemm_qkv<<<1152, 256, 0, stream>>>(xb, wqb, bqkv, Qb, Kb, Vb);

  mask_to_bits<<<2048, 256, 0, stream>>>(mask, mbits);

  vtrans<<<dim3(16, 96), 256, 0, stream>>>(Vb, Vtb);

  attn_kernel<<<dim3(8, 96), 512, 0, stream>>>(Qb, Kb, Vtb, rel_pos_bias,
                                               (const unsigned*)mbits, out1, ctx);

  gemm_proj<<<384, 256, 0, stream>>>(ctx, wpb, bproj, out0);
}